// Round 6
// baseline (269.531 us; speedup 1.0000x reference)
//
#include <hip/hip_runtime.h>
#include <cstdint>
#include <cstddef>

// Problem constants
constexpr int kB  = 16;
constexpr int kS  = 784;
constexpr int kD  = 768;
constexpr int kH  = 12;
constexpr int kM  = kB * kS;    // 12544
constexpr int kSP = 832;        // padded seq (13*64) for Vt cols

typedef __attribute__((ext_vector_type(8))) short bf16x8;
typedef __attribute__((ext_vector_type(4))) float floatx4;

__device__ __forceinline__ unsigned short f2bf(float x) {
    union { float f; unsigned int u; } v; v.f = x;
    unsigned int r = v.u + 0x7fffu + ((v.u >> 16) & 1u);  // RTNE
    return (unsigned short)(r >> 16);
}
__device__ __forceinline__ float bf2f(unsigned short h) {
    union { unsigned int u; float f; } v; v.u = ((unsigned int)h) << 16;
    return v.f;
}

// Raw 2^x: v_exp_f32 with no OCML denormal guard. Inputs bounded.
__device__ __forceinline__ float fast_exp2(float x) {
#if __has_builtin(__builtin_amdgcn_exp2f)
    return __builtin_amdgcn_exp2f(x);
#else
    return __expf(x * 0.69314718055994531f);
#endif
}

// v_cvt_pk_bf16_f32: pack two f32 -> u32 of 2 bf16 (lo = first operand).
__device__ __forceinline__ unsigned cvtpk(float lo, float hi) {
    unsigned r;
    asm("v_cvt_pk_bf16_f32 %0, %1, %2" : "=v"(r) : "v"(lo), "v"(hi));
    return r;
}
// permlane swaps (gfx950): both operands read-write.
__device__ __forceinline__ void pl32(unsigned &a, unsigned &b) {
    asm("v_permlane32_swap_b32 %0, %1" : "+v"(a), "+v"(b));
}
__device__ __forceinline__ void pl16(unsigned &a, unsigned &b) {
    asm("v_permlane16_swap_b32 %0, %1" : "+v"(a), "+v"(b));
}
__device__ __forceinline__ bf16x8 mk8(unsigned a, unsigned b, unsigned c, unsigned d) {
    union { unsigned u[4]; bf16x8 v; } f;
    f.u[0] = a; f.u[1] = b; f.u[2] = c; f.u[3] = d; return f.v;
}

// async global->LDS, 16B/lane; LDS dst = base(wave-uniform) + lane*16
__device__ __forceinline__ void gload_lds16(const void* g, void* l) {
    __builtin_amdgcn_global_load_lds(
        (const __attribute__((address_space(1))) void*)g,
        (__attribute__((address_space(3))) void*)l,
        16, 0, 0);
}

// ---------------------------------------------------------------------------
// Pre-pass: hs -> bf16; wq|wk|wv|wo -> bf16 concat; rot -> packed bf16 cos|sin
// uint table; bq|bk|bv -> concat fp32. Grid 12505 x 256.
// ---------------------------------------------------------------------------
constexpr int kHsF4   = (kM * kD) / 4;        // 2,408,448
constexpr int kWF4    = (kD * kD) / 4;        // 147,456
constexpr int kPreTot = kHsF4 + 4 * kWF4 + (kM * 64) / 4;  // 3,198,976

__global__ __launch_bounds__(256)
void convert_pre(const float* __restrict__ hs, const float* __restrict__ rot,
                 const float* __restrict__ wq, const float* __restrict__ wk,
                 const float* __restrict__ wv, const float* __restrict__ wo,
                 const float* __restrict__ bq, const float* __restrict__ bk,
                 const float* __restrict__ bv,
                 unsigned short* __restrict__ hsB, unsigned short* __restrict__ wB,
                 unsigned int* __restrict__ csT, float* __restrict__ biasC)
{
    const int i = blockIdx.x * 256 + threadIdx.x;
    if (i < kHsF4) {
        float4 v = ((const float4*)hs)[i];
        ushort4 o = { f2bf(v.x), f2bf(v.y), f2bf(v.z), f2bf(v.w) };
        ((ushort4*)hsB)[i] = o;
    } else if (i < kHsF4 + 4 * kWF4) {
        const int j = i - kHsF4;
        const int w = j / kWF4, jj = j - w * kWF4;
        const float* src = (w == 0) ? wq : (w == 1) ? wk : (w == 2) ? wv : wo;
        float4 v = ((const float4*)src)[jj];
        ushort4 o = { f2bf(v.x), f2bf(v.y), f2bf(v.z), f2bf(v.w) };
        ((ushort4*)(wB + (size_t)w * (kD * kD)))[jj] = o;
    } else if (i < kPreTot) {
        const int j = i - kHsF4 - 4 * kWF4;
        float4 v = ((const float4*)rot)[j];
        float a[4] = { v.x, v.y, v.z, v.w };
        #pragma unroll
        for (int e = 0; e < 4; ++e) {
            float s, c;
            __sincosf(a[e], &s, &c);
            csT[j * 4 + e] = (unsigned)f2bf(c) | ((unsigned)f2bf(s) << 16);
        }
    } else {
        const int j = i - kPreTot;
        if (j < 3 * kD)
            biasC[j] = (j < kD) ? bq[j] : (j < 2 * kD) ? bk[j - kD] : bv[j - 2 * kD];
    }
}

// ---------------------------------------------------------------------------
// 128x128xBK32 bf16 GEMM-NT, 256 threads = 4 waves (wave tile 64x64, acc 4x4
// = 64 VGPR -> 3 waves/SIMD budget). LDS 48KB = 3 bufs x {A 8K | B 8K},
// 256x.. rows of 64B, chunk swizzle chunk^=((row>>1)&3) (2-way = free),
// staged via pre-swizzled GLOBAL source + linear global_load_lds (rule #21).
// 3 blocks/CU co-resident: cross-block overlap hides barriers/waits (m114).
// Prefetch distance 2, counted vmcnt(4) per tile (T4: drain 4->0 only at
// tail). Per K-tile: {stage kt+2; ds_read cur; BARR; lgk0; prio1; 16 MFMA;
// prio0; vmcnt(4); BARR}.
// Grid: QKV 98x18=1764 blocks (6.9/CU -> 1.6% quantization), OUT 98x6=588.
// QKV epilogue pre-scales Q by 0.125*log2(e) so flash_attn uses raw v_exp.
// ---------------------------------------------------------------------------
enum { MODE_QKV = 0, MODE_OUT = 1 };

#define BARR  __builtin_amdgcn_s_barrier()
#define LGK0  asm volatile("s_waitcnt lgkmcnt(0)" ::: "memory")
#define VM4   asm volatile("s_waitcnt vmcnt(4)" ::: "memory")
#define VM0   asm volatile("s_waitcnt vmcnt(0)" ::: "memory")
#define PRIO1 __builtin_amdgcn_s_setprio(1)
#define PRIO0 __builtin_amdgcn_s_setprio(0)

// One K-tile. CUR = read buf (0/1/2), NX2 = (kt+2)%3, KT runtime tile idx.
#define KTILE4(CUR, NX2, KT) do{ \
    if ((KT) <= 21) stg((KT) + 2, NX2); \
    _Pragma("unroll") for (int m = 0; m < 4; ++m) \
        afr[m] = *(const bf16x8*)(rdA + (CUR)*16384 + m*1024); \
    _Pragma("unroll") for (int nt = 0; nt < 4; ++nt) \
        bfr[nt] = *(const bf16x8*)(rdB + (CUR)*16384 + nt*1024); \
    BARR; LGK0; PRIO1; \
    _Pragma("unroll") for (int m = 0; m < 4; ++m) \
        _Pragma("unroll") for (int nt = 0; nt < 4; ++nt) \
            acc[m][nt] = __builtin_amdgcn_mfma_f32_16x16x32_bf16( \
                afr[m], bfr[nt], acc[m][nt], 0, 0, 0); \
    PRIO0; \
    if ((KT) <= 21) { VM4; } else if ((KT) == 22) { VM0; } \
    BARR; \
}while(0)

template<int MODE>
__global__ __launch_bounds__(256, 3)
void gemm4(const unsigned short* __restrict__ A, const unsigned short* __restrict__ W,
           const float* __restrict__ bias, const unsigned int* __restrict__ csT,
           unsigned short* __restrict__ Qp, unsigned short* __restrict__ Kp,
           unsigned short* __restrict__ Vtp, float* __restrict__ Op)
{
    constexpr int NTL = (MODE == MODE_QKV) ? 18 : 6;   // 128-wide n tiles

    __shared__ unsigned short SM[24576];   // 48 KB: buf b: A @ b*16K, B @ +8K

    const int lin    = blockIdx.x;
    const int m_tile = lin / NTL;
    const int n_tile = lin - m_tile * NTL;
    const int m0 = m_tile * 128;
    const int n0 = n_tile * 128;

    const int tid  = threadIdx.x;
    const int wave = tid >> 6;          // 0..3
    const int lane = tid & 63;
    const int quad = lane >> 4, l16 = lane & 15;
    const int wm = wave & 1;            // row half
    const int wn = wave >> 1;           // col half

    // ---- staging (pre-swizzled global source, linear LDS dst)
    // thread (w,l), gll g: LDS row = g*64 + w*16 + (l>>2), chunk c = l&3;
    // source chunk = c ^ s(row), s(row) = (l>>3)&3.
    const int srow = wave * 16 + (lane >> 2);
    const int sc   = (lane & 3) ^ ((lane >> 3) & 3);
    const unsigned short* gA0 = A + (size_t)(m0 + srow) * kD + sc * 8;
    const unsigned short* gA1 = gA0 + (size_t)64 * kD;
    const unsigned short* gB0 = W + (size_t)(n0 + srow) * kD + sc * 8;
    const unsigned short* gB1 = gB0 + (size_t)64 * kD;
    char* smc = (char*)SM;

    auto stg = [&](int kt, int buf) {
        const int off = kt * 32;
        char* base = smc + buf * 16384;
        gload_lds16(gA0 + off, base + wave * 1024);
        gload_lds16(gA1 + off, base + 4096  + wave * 1024);
        gload_lds16(gB0 + off, base + 8192  + wave * 1024);
        gload_lds16(gB1 + off, base + 12288 + wave * 1024);
    };

    // ---- compute-side lane bases (ds_read = base + buf/frag immediates)
    const int sw = (quad ^ ((l16 >> 1) & 3)) * 16;
    const char* rdA = smc + (wm * 64 + l16) * 64 + sw;
    const char* rdB = smc + 8192 + (wn * 64 + l16) * 64 + sw;

    floatx4 acc[4][4];
    #pragma unroll
    for (int m = 0; m < 4; ++m)
        #pragma unroll
        for (int nt = 0; nt < 4; ++nt)
            acc[m][nt] = {0.f, 0.f, 0.f, 0.f};
    bf16x8 afr[4], bfr[4];

    // ---- prologue: batches 0,1 into bufs 0,1 (prefetch depth 2)
    stg(0, 0);
    stg(1, 1);
    VM4;          // batch 0 retired (own); batch 1 in flight
    BARR;         // all waves' batch 0 visible

    // ---- 24 K-tiles, bufs cycle 0,1,2
    for (int t8 = 0; t8 < 8; ++t8) {
        const int kt = t8 * 3;
        KTILE4(0, 2, kt);
        KTILE4(1, 0, kt + 1);
        KTILE4(2, 1, kt + 2);
    }

    // ---- epilogue
    if constexpr (MODE == MODE_OUT) {
        #pragma unroll
        for (int nt = 0; nt < 4; ++nt) {
            const int n = n0 + wn * 64 + nt * 16 + l16;
            const float bv = bias[n];
            #pragma unroll
            for (int m = 0; m < 4; ++m)
                #pragma unroll
                for (int r = 0; r < 4; ++r) {
                    const int mm = m0 + wm * 64 + m * 16 + quad * 4 + r;
                    Op[(size_t)mm * kD + n] = acc[m][nt][r] + bv;
                }
        }
    } else {
        const int proj = n_tile / 6;   // 0=Q, 1=K, 2=V (block-uniform)
        if (proj < 2) {
            unsigned short* dst = proj ? Kp : Qp;
            // Q: fold softmax scale AND log2(e) so attention uses raw v_exp.
            const float scale = proj ? 1.0f : 0.125f * 1.44269504088896341f;
            #pragma unroll
            for (int nt = 0; nt < 4; ++nt) {
                const int n = n0 + wn * 64 + nt * 16 + l16;
                const float bv = bias[n];
                const int col = n - proj * kD;
                const int dh = col & 63;
                const int odd = l16 & 1;
                #pragma unroll
                for (int m = 0; m < 4; ++m)
                    #pragma unroll
                    for (int r = 0; r < 4; ++r) {
                        const int mm = m0 + wm * 64 + m * 16 + quad * 4 + r;
                        const float val = acc[m][nt][r] + bv;
                        const float px = __shfl_xor(val, 1);
                        const unsigned u = csT[(size_t)mm * 64 + dh];
                        const float c = bf2f((unsigned short)(u & 0xffffu));
                        const float s = bf2f((unsigned short)(u >> 16));
                        const float out = odd ? (val * c + px * s) : (val * c - px * s);
                        dst[(size_t)mm * kD + col] = f2bf(out * scale);
                    }
            }
        } else {
            #pragma unroll
            for (int nt = 0; nt < 4; ++nt) {
                const int n = n0 + wn * 64 + nt * 16 + l16;
                const float bv = bias[n];
                const int col = n - 2 * kD;
                const int h = col >> 6, dh = col & 63;
                #pragma unroll
                for (int m = 0; m < 4; ++m) {
                    const int m_r0 = m0 + wm * 64 + m * 16 + quad * 4;
                    const int b = m_r0 / kS;
                    const int s = m_r0 - b * kS;
                    ushort4 pk;
                    pk.x = f2bf(acc[m][nt][0] + bv);
                    pk.y = f2bf(acc[m][nt][1] + bv);
                    pk.z = f2bf(acc[m][nt][2] + bv);
                    pk.w = f2bf(acc[m][nt][3] + bv);
                    *(ushort4*)(Vtp + (size_t)((b * kH + h) * 64 + dh) * kSP + s) = pk;
                }
            }
        }
    }
}

// ---------------------------------------------------------------------------
// Flash attention: BR=128 (wave owns 32 q rows), BC=64, no online max
// (scores bounded; Q pre-scaled 0.125*log2e -> P = 2^S' via raw v_exp_f32).
// T12 (swapped QK^T): mfma(K,Q) -> lane owns q-row; P stays in registers via
// cvt_pk + permlane32/16 swap composition -> PV A-fragments. No Ps LDS.
// Row-sum on the MATRIX pipe (MFMA vs all-ones B on the same ap fragments).
// K/V triple-buffered, prefetch depth 2, counted vmcnt: tail 8->4->0.
// ---------------------------------------------------------------------------
__global__ __launch_bounds__(256)
void flash_attn(const unsigned short* __restrict__ Qg,
                const unsigned short* __restrict__ Kg,
                const unsigned short* __restrict__ Vtg,
                unsigned short* __restrict__ Og)
{
    __shared__ unsigned short KV[3][8192];   // [buf]: K rows @ [0], V @ [4096]

    const int lin   = blockIdx.x;            // 0..1343 (192 bh x 7 qt)
    const int group = lin / 56;
    const int rem   = lin - group * 56;
    const int bh = group * 8 + (rem & 7);
    const int qt = rem >> 3;
    const int b = bh / kH, h = bh - b * kH;
    const int tid = threadIdx.x, wave = tid >> 6, lane = tid & 63;
    const int quad = lane >> 4, l16 = lane & 15;
    const int q0 = qt * 128;
    const size_t rowBase = (size_t)(b * kS) * kD + h * 64;

    // ---- stage Q (128x64, 16KB) into KV[0] flat, swizzled, via gll
    #pragma unroll
    for (int j = 0; j < 4; ++j) {
        const int idx = (wave * 4 + j) * 64 + lane;
        const int row = idx >> 3, slot = idx & 7, seg = slot ^ (row & 7);
        gload_lds16(Qg + rowBase + (size_t)(q0 + row) * kD + seg * 8,
                    &KV[0][(wave * 4 + j) * 512]);
    }
    __syncthreads();
    bf16x8 aq[2][2];
    #pragma unroll
    for (int mt = 0; mt < 2; ++mt)
        #pragma unroll
        for (int ch = 0; ch < 2; ++ch) {
            const int row = wave * 32 + mt * 16 + l16;
            const int slot = (ch * 4 + quad) ^ (row & 7);
            aq[mt][ch] = *(const bf16x8*)&KV[0][row * 64 + slot * 8];
        }
    __syncthreads();   // aq reads drained before prologue overwrites KV[0]

    // staging chunk geometry (per tile: 512 chunks, 2 per thread)
    const int cidx0 = wave * 128 + lane;
    const int crow0 = cidx0 >> 3, cseg0 = (cidx0 & 7) ^ (crow0 & 7);
    const int cidx1 = cidx0 + 64;
    const int crow1 = cidx1 >> 3, cseg1 = (cidx1 & 7) ^ (crow1 & 7);

    // stage one K/V tile (4 gll per thread) into buffer `buf`
    auto stage = [&](int kt, int buf) {
        const int kr = kt * 64;
        gload_lds16(Kg + rowBase + (size_t)(kr + crow0) * kD + cseg0 * 8,
                    &KV[buf][wave * 1024]);
        gload_lds16(Vtg + (size_t)(bh * 64 + crow0) * kSP + kr + cseg0 * 8,
                    &KV[buf][4096 + wave * 1024]);
        gload_lds16(Kg + rowBase + (size_t)(kr + crow1) * kD + cseg1 * 8,
                    &KV[buf][wave * 1024 + 512]);
        gload_lds16(Vtg + (size_t)(bh * 64 + crow1) * kSP + kr + cseg1 * 8,
                    &KV[buf][4096 + wave * 1024 + 512]);
    };

    // prologue: batches 0,1 into buf0,buf1 (prefetch depth 2)
    stage(0, 0);
    stage(1, 1);

    floatx4 oacc[2][4];
    #pragma unroll
    for (int mt = 0; mt < 2; ++mt)
        #pragma unroll
        for (int nt = 0; nt < 4; ++nt)
            oacc[mt][nt] = {0.f, 0.f, 0.f, 0.f};
    floatx4 lsum[2];
    lsum[0] = {0.f, 0.f, 0.f, 0.f};
    lsum[1] = {0.f, 0.f, 0.f, 0.f};
    const bf16x8 onesb = { 16256, 16256, 16256, 16256,
                           16256, 16256, 16256, 16256 };   // bf16 1.0 x8

    int cur = 0;   // kt % 3
    int pre = 2;   // (kt+2) % 3
    for (int kt = 0; kt < 13; ++kt) {
        asm volatile("s_barrier" ::: "memory");   // WAR: readers of buf[pre] done
        if (kt < 11) stage(kt + 2, pre);
        if (kt < 11)       asm volatile("s_waitcnt vmcnt(8)" ::: "memory");
        else if (kt == 11) asm volatile("s_waitcnt vmcnt(4)" ::: "memory");
        else               asm volatile("s_waitcnt vmcnt(0)" ::: "memory");
        asm volatile("s_barrier" ::: "memory");   // RAW: batch kt visible to all

        const unsigned short* Ks = &KV[cur][0];
        const unsigned short* Vs = &KV[cur][4096];

        // S^T = K Q^T  (swapped): lane(quad,l16) reg r of sc[nt][mt] =
        //   S[k = nt*16+quad*4+r][q = mt*16+l16]
        bf16x8 bk[4][2];
        #pragma unroll
        for (int nt = 0; nt < 4; ++nt)
            #pragma unroll
            for (int ch = 0; ch < 2; ++ch) {
                const int row = nt * 16 + l16;
                const int slot = (ch * 4 + quad) ^ (row & 7);
                bk[nt][ch] = *(const bf16x8*)&Ks[row * 64 + slot * 8];
            }

        floatx4 sc[4][2];
        __builtin_amdgcn_s_setprio(1);
        #pragma unroll
        for (int nt = 0; nt < 4; ++nt)
            #pragma unroll
            for (int mt = 0; mt < 2; ++mt) {
                sc[nt][mt] = {0.f, 0.f, 0.f, 0.f};
                sc[nt][mt] = __builtin_amdgcn_mfma_f32_16x16x32_bf16(
                    bk[nt][0], aq[mt][0], sc[nt][mt], 0, 0, 0);
                sc[nt][mt] = __builtin_amdgcn_mfma_f32_16x16x32_bf16(
                    bk[nt][1], aq[mt][1], sc[nt][mt], 0, 0, 0);
            }
        __builtin_amdgcn_s_setprio(0);

        if (kt == 12) {   // valid keys 768..783 = local k 0..15 (nt==0 only)
            #pragma unroll
            for (int nt = 1; nt < 4; ++nt)
                #pragma unroll
                for (int mt = 0; mt < 2; ++mt)
                    #pragma unroll
                    for (int r = 0; r < 4; ++r) sc[nt][mt][r] = -1e30f;
        }

        // P = 2^S' (raw v_exp), in place
        #pragma unroll
        for (int nt = 0; nt < 4; ++nt)
            #pragma unroll
            for (int mt = 0; mt < 2; ++mt)
                #pragma unroll
                for (int r = 0; r < 4; ++r)
                    sc[nt][mt][r] = fast_exp2(sc[nt][mt][r]);

        // In-register P -> PV A-fragments via cvt_pk + permlane swaps.
        bf16x8 ap[2][2];
        #pragma unroll
        for (int mt = 0; mt < 2; ++mt) {
            unsigned L0 = cvtpk(sc[0][mt][0], sc[0][mt][1]);
            unsigned H0 = cvtpk(sc[0][mt][2], sc[0][mt][3]);
            unsigned L1 = cvtpk(sc[1][mt][0], sc[1][mt][1]);
            unsigned H1 = cvtpk(sc[1][mt][2], sc[1][mt][3]);
            unsigned L2 = cvtpk(sc[2][mt][0], sc[2][mt][1]);
            unsigned H2 = cvtpk(sc[2][mt][2], sc[2][mt][3]);
            unsigned L3 = cvtpk(sc[3][mt][0], sc[3][mt][1]);
            unsigned H3 = cvtpk(sc[3][mt][2], sc[3][mt][3]);
            pl32(L0, L1); pl16(L0, L1);   // ks=0
            pl32(H0, H1); pl16(H0, H1);
            ap[mt][0] = mk8(L0, H0, L1, H1);
            pl32(L2, L3); pl16(L2, L3);   // ks=1
            pl32(H2, H3); pl16(H2, H3);
            ap[mt][1] = mk8(L2, H2, L3, H3);
        }

        // O += P V ; lsum += P * 1
        __builtin_amdgcn_s_setprio(1);
        #pragma unroll
        for (int ks = 0; ks < 2; ++ks) {
            #pragma unroll
            for (int nt = 0; nt < 4; ++nt) {
                const int row = nt * 16 + l16;
                const int slot = (ks * 4 + quad) ^ (row & 7);
                const bf16x8 bv = *(const bf16x8*)&Vs[row * 64 + slot * 8];
                #pragma unroll
                for (int mt = 0; mt < 2; ++mt)
                    oacc[mt][nt] = __builtin_amdgcn_mfma_f32_16x16x32_bf16(
                        ap[mt][ks], bv, oacc[mt][nt], 0, 0, 0);
            }
            #pragma unroll
            for (int mt = 0; mt < 2; ++mt)
                lsum[mt] = __builtin_amdgcn_mfma_f32_16x16x32_bf16(
                    ap[mt][ks], onesb, lsum[mt], 0, 0, 0);
        }
        __builtin_amdgcn_s_setprio(0);

        cur = (cur == 2) ? 0 : cur + 1;
        pre = (pre == 2) ? 0 : pre + 1;
    }

    // lsum lane layout == oacc lane layout: reg r <-> q-row quad*4+r.
    #pragma unroll
    for (int mt = 0; mt < 2; ++mt)
        #pragma unroll
        for (int r = 0; r < 4; ++r) {
            const int srow = q0 + wave * 32 + mt * 16 + quad * 4 + r;
            if (srow < kS) {
                const float inv = 1.0f / lsum[mt][r];
                #pragma unroll
                for (int nt = 0; nt < 4; ++nt)
                    Og[rowBase + (size_t)srow * kD + nt * 16 + l16] =
                        f2bf(oacc[mt][nt][r] * inv);
            }
        }
}

// ---------------------------------------------------------------------------
extern "C" void kernel_launch(void* const* d_in, const int* in_sizes, int n_in,
                              void* d_out, int out_size, void* d_ws, size_t ws_size,
                              hipStream_t stream)
{
    (void)in_sizes; (void)n_in; (void)out_size; (void)ws_size;
    const float* hs  = (const float*)d_in[0];
    const float* rot = (const float*)d_in[1];
    const float* wq  = (const float*)d_in[2];
    const float* bq  = (const float*)d_in[3];
    const float* wk  = (const float*)d_in[4];
    const float* bk  = (const float*)d_in[5];
    const float* wv  = (const float*)d_in[6];
    const float* bv  = (const float*)d_in[7];
    const float* wo  = (const float*)d_in[8];
    const float* bo  = (const float*)d_in[9];

    char* ws = (char*)d_ws;
    // Layout (bytes):
    //   hsB/O : 0          .. 19,267,584   (bf16 [12544,768]; O aliases after QKV)
    //   wB    : 19,267,584 .. 23,986,176   (wq|wk|wv|wo bf16 = [2304+768, 768])
    //   csT   : 23,986,176 .. 27,197,440   (uint cos|sin bf16 [12544,64])
    //   biasC : 27,197,440 .. 27,206,656   (bq|bk|bv fp32)
    //   Q     : 27,206,656 .. 46,474,240
    //   K     : 46,474,240 .. 65,741,824
    //   Vt    : 65,741,824 .. 86,189,056   (bf16 [192*64, 832])
    unsigned short* hsB  = (unsigned short*)ws;
    unsigned short* wB   = (unsigned short*)(ws + 19267584);
    unsigned int*   csT  = (unsigned int*)(ws + 23986176);
    float*          biasC= (float*)(ws + 27197440);
    unsigned short* Q    = (unsigned short*)(ws + 27206656);
    unsigned short* K    = (unsigned short*)(ws + 46474240);
    unsigned short* Vt   = (unsigned short*)(ws + 65741824);
    unsigned short* O    = hsB;  // hsB dead after QKV GEMM

    convert_pre<<<dim3(12505), dim3(256), 0, stream>>>(hs, rot, wq, wk, wv, wo, bq, bk, bv,
                                                       hsB, wB, csT, biasC);
    // QKV: 98 m-tiles x 18 n-tiles = 1764 blocks, 3/CU
    gemm4<MODE_QKV><<<dim3(1764), dim3(256), 0, stream>>>(
        hsB, wB, biasC, csT, Q, K, Vt, nullptr);
    flash_attn<<<dim3(7 * 192), dim3(256), 0, stream>>>(Q, K, Vt, O);
    // OUT: 98 x 6 = 588 blocks
    gemm4<MODE_OUT><<<dim3(588), dim3(256), 0, stream>>>(
        O, wB + 3 * kD * kD, bo, nullptr, nullptr, nullptr, nullptr, (float*)d_out);
}

// Round 7
// 227.728 us; speedup vs baseline: 1.1836x; 1.1836x over previous
//
#include <hip/hip_runtime.h>
#include <cstdint>
#include <cstddef>

// Problem constants
constexpr int kB  = 16;
constexpr int kS  = 784;
constexpr int kD  = 768;
constexpr int kH  = 12;
constexpr int kM  = kB * kS;    // 12544
constexpr int kSP = 832;        // padded seq (13*64) for Vt cols

typedef __attribute__((ext_vector_type(8))) short bf16x8;
typedef __attribute__((ext_vector_type(4))) float floatx4;

__device__ __forceinline__ unsigned short f2bf(float x) {
    union { float f; unsigned int u; } v; v.f = x;
    unsigned int r = v.u + 0x7fffu + ((v.u >> 16) & 1u);  // RTNE
    return (unsigned short)(r >> 16);
}
__device__ __forceinline__ float bf2f(unsigned short h) {
    union { unsigned int u; float f; } v; v.u = ((unsigned int)h) << 16;
    return v.f;
}

// Raw 2^x: v_exp_f32 with no OCML denormal guard. Inputs bounded.
__device__ __forceinline__ float fast_exp2(float x) {
#if __has_builtin(__builtin_amdgcn_exp2f)
    return __builtin_amdgcn_exp2f(x);
#else
    return __expf(x * 0.69314718055994531f);
#endif
}

// v_cvt_pk_bf16_f32: pack two f32 -> u32 of 2 bf16 (lo = first operand).
__device__ __forceinline__ unsigned cvtpk(float lo, float hi) {
    unsigned r;
    asm("v_cvt_pk_bf16_f32 %0, %1, %2" : "=v"(r) : "v"(lo), "v"(hi));
    return r;
}
// permlane swaps (gfx950): both operands read-write.
__device__ __forceinline__ void pl32(unsigned &a, unsigned &b) {
    asm("v_permlane32_swap_b32 %0, %1" : "+v"(a), "+v"(b));
}
__device__ __forceinline__ void pl16(unsigned &a, unsigned &b) {
    asm("v_permlane16_swap_b32 %0, %1" : "+v"(a), "+v"(b));
}
__device__ __forceinline__ bf16x8 mk8(unsigned a, unsigned b, unsigned c, unsigned d) {
    union { unsigned u[4]; bf16x8 v; } f;
    f.u[0] = a; f.u[1] = b; f.u[2] = c; f.u[3] = d; return f.v;
}

// async global->LDS, 16B/lane; LDS dst = base(wave-uniform) + lane*16
__device__ __forceinline__ void gload_lds16(const void* g, void* l) {
    __builtin_amdgcn_global_load_lds(
        (const __attribute__((address_space(1))) void*)g,
        (__attribute__((address_space(3))) void*)l,
        16, 0, 0);
}

// ---------------------------------------------------------------------------
// Pre-pass: hs -> bf16; wq|wk|wv|wo -> bf16 concat; rot -> packed bf16 cos|sin
// uint table; bq|bk|bv -> concat fp32. Grid 12505 x 256.
// ---------------------------------------------------------------------------
constexpr int kHsF4   = (kM * kD) / 4;        // 2,408,448
constexpr int kWF4    = (kD * kD) / 4;        // 147,456
constexpr int kPreTot = kHsF4 + 4 * kWF4 + (kM * 64) / 4;  // 3,198,976

__global__ __launch_bounds__(256)
void convert_pre(const float* __restrict__ hs, const float* __restrict__ rot,
                 const float* __restrict__ wq, const float* __restrict__ wk,
                 const float* __restrict__ wv, const float* __restrict__ wo,
                 const float* __restrict__ bq, const float* __restrict__ bk,
                 const float* __restrict__ bv,
                 unsigned short* __restrict__ hsB, unsigned short* __restrict__ wB,
                 unsigned int* __restrict__ csT, float* __restrict__ biasC)
{
    const int i = blockIdx.x * 256 + threadIdx.x;
    if (i < kHsF4) {
        float4 v = ((const float4*)hs)[i];
        ushort4 o = { f2bf(v.x), f2bf(v.y), f2bf(v.z), f2bf(v.w) };
        ((ushort4*)hsB)[i] = o;
    } else if (i < kHsF4 + 4 * kWF4) {
        const int j = i - kHsF4;
        const int w = j / kWF4, jj = j - w * kWF4;
        const float* src = (w == 0) ? wq : (w == 1) ? wk : (w == 2) ? wv : wo;
        float4 v = ((const float4*)src)[jj];
        ushort4 o = { f2bf(v.x), f2bf(v.y), f2bf(v.z), f2bf(v.w) };
        ((ushort4*)(wB + (size_t)w * (kD * kD)))[jj] = o;
    } else if (i < kPreTot) {
        const int j = i - kHsF4 - 4 * kWF4;
        float4 v = ((const float4*)rot)[j];
        float a[4] = { v.x, v.y, v.z, v.w };
        #pragma unroll
        for (int e = 0; e < 4; ++e) {
            float s, c;
            __sincosf(a[e], &s, &c);
            csT[j * 4 + e] = (unsigned)f2bf(c) | ((unsigned)f2bf(s) << 16);
        }
    } else {
        const int j = i - kPreTot;
        if (j < 3 * kD)
            biasC[j] = (j < kD) ? bq[j] : (j < 2 * kD) ? bk[j - kD] : bv[j - 2 * kD];
    }
}

// ---------------------------------------------------------------------------
// 8-phase 256x256xBK64 bf16 GEMM-NT (m201 template, plain HIP) — round-5
// known-good revert (round-6's 128^2 tile tripled L2-miss traffic and became
// traffic-bound). 512 threads = 8 waves.
// ---------------------------------------------------------------------------
enum { MODE_QKV = 0, MODE_OUT = 1 };

#define BARR  __builtin_amdgcn_s_barrier()
#define LGK0  asm volatile("s_waitcnt lgkmcnt(0)" ::: "memory")
#define VM4   asm volatile("s_waitcnt vmcnt(4)" ::: "memory")
#define VM0   asm volatile("s_waitcnt vmcnt(0)" ::: "memory")
#define PRIO1 __builtin_amdgcn_s_setprio(1)
#define PRIO0 __builtin_amdgcn_s_setprio(0)

#define LDA4(KS, RB, MQ) do{ \
  afr[0]=*(const bf16x8*)(rdA##KS+(RB)+((MQ)+0)*4096); \
  afr[1]=*(const bf16x8*)(rdA##KS+(RB)+((MQ)+1)*4096); \
  afr[2]=*(const bf16x8*)(rdA##KS+(RB)+((MQ)+2)*4096); \
  afr[3]=*(const bf16x8*)(rdA##KS+(RB)+((MQ)+3)*4096); }while(0)

#define LDB4(KS, RB) do{ \
  bfr[0]=*(const bf16x8*)(rdB##KS+(RB)); \
  bfr[1]=*(const bf16x8*)(rdB##KS+(RB)+8192); \
  bfr[2]=*(const bf16x8*)(rdB##KS+(RB)+16384); \
  bfr[3]=*(const bf16x8*)(rdB##KS+(RB)+24576); }while(0)

#define MFMA16(MQ) do{ _Pragma("unroll") for(int nt=0;nt<4;++nt){ \
  acc[(MQ)  ][nt]=__builtin_amdgcn_mfma_f32_16x16x32_bf16(afr[0],bfr[nt],acc[(MQ)  ][nt],0,0,0); \
  acc[(MQ)+1][nt]=__builtin_amdgcn_mfma_f32_16x16x32_bf16(afr[1],bfr[nt],acc[(MQ)+1][nt],0,0,0); \
  acc[(MQ)+2][nt]=__builtin_amdgcn_mfma_f32_16x16x32_bf16(afr[2],bfr[nt],acc[(MQ)+2][nt],0,0,0); \
  acc[(MQ)+3][nt]=__builtin_amdgcn_mfma_f32_16x16x32_bf16(afr[3],bfr[nt],acc[(MQ)+3][nt],0,0,0); \
}}while(0)

// One K-tile = 4 phases. RB = read-buffer byte offset, SB = other buffer.
#define KTILE(RB, SB, KT) do{ \
  /* p0 */ LDA4(0, RB, 0); LDB4(0, RB); \
    if ((KT) <= 10) { stA(1, (KT)+1, SB); stB(1, (KT)+1, SB); } \
    BARR; LGK0; PRIO1; MFMA16(0); PRIO0; BARR; \
  /* p1 */ LDA4(0, RB, 4); \
    BARR; LGK0; PRIO1; MFMA16(4); PRIO0; BARR; \
  /* p2 */ LDA4(1, RB, 0); LDB4(1, RB); \
    BARR; LGK0; PRIO1; MFMA16(0); PRIO0; BARR; \
  /* p3 */ LDA4(1, RB, 4); \
    if ((KT) <= 9) { stA(0, (KT)+2, RB); stB(0, (KT)+2, RB); VM4; } \
    else if ((KT) == 10) { VM0; } \
    BARR; LGK0; PRIO1; MFMA16(4); PRIO0; BARR; \
}while(0)

template<int MODE>
__global__ __launch_bounds__(512, 2)
void gemm8(const unsigned short* __restrict__ A, const unsigned short* __restrict__ W,
           const float* __restrict__ bias, const unsigned int* __restrict__ csT,
           unsigned short* __restrict__ Qp, unsigned short* __restrict__ Kp,
           unsigned short* __restrict__ Vtp, float* __restrict__ Op)
{
    constexpr int NTL = (MODE == MODE_QKV) ? 9 : 3;   // 256-wide n tiles

    __shared__ unsigned short SM[65536];   // 128 KB

    // raster: 6 groups of 8 m-tiles x NTL n-tiles, tail group = m_tile 48
    const int lin   = blockIdx.x;
    const int group = lin / (8 * NTL);
    const int rem   = lin - group * (8 * NTL);
    int m_tile, n_tile;
    if (group < 6) { m_tile = group * 8 + (rem & 7); n_tile = rem >> 3; }
    else           { m_tile = 48; n_tile = rem; }
    const int m0 = m_tile * 256;
    const int n0 = n_tile * 256;

    const int tid  = threadIdx.x;
    const int wave = tid >> 6;          // 0..7
    const int lane = tid & 63;
    const int quad = lane >> 4, l16 = lane & 15;
    const int wm = wave & 1;            // 16-row interleave
    const int wn = wave >> 1;           // 0..3, 16-col interleave within nt*64

    // ---- staging constants (pre-swizzled global source, linear LDS dst)
    const int l8  = lane >> 3;                 // 0..7
    const int sc  = (lane & 7) ^ l8;           // swizzled source chunk
    const unsigned short* gA0 = A + (size_t)(m0 + wave * 16 + l8) * kD + sc * 8;
    const unsigned short* gA1 = gA0 + (size_t)8 * kD;
    const unsigned short* gB0 = W + (size_t)(n0 + wave * 16 + l8) * kD + sc * 8;
    const unsigned short* gB1 = gB0 + (size_t)8 * kD;
    char* smc = (char*)SM;

    auto stA = [&](int h, int kt, int bufoff) {
        const int off = h * 98304 + kt * 64;
        gload_lds16(gA0 + off, smc + bufoff + h * 16384 + wave * 2048);
        gload_lds16(gA1 + off, smc + bufoff + h * 16384 + wave * 2048 + 1024);
    };
    auto stB = [&](int h, int kt, int bufoff) {
        const int off = h * 98304 + kt * 64;
        gload_lds16(gB0 + off, smc + 65536 + bufoff + h * 16384 + wave * 2048);
        gload_lds16(gB1 + off, smc + 65536 + bufoff + h * 16384 + wave * 2048 + 1024);
    };

    // ---- compute-side lane bases (all ds_read = base + immediate)
    const int swz0 = ((quad    ) ^ (l16 & 7)) * 16;
    const int swz1 = ((quad + 4) ^ (l16 & 7)) * 16;
    const char* rdA0 = (const char*)SM + (wm * 16 + l16) * 128 + swz0;
    const char* rdA1 = (const char*)SM + (wm * 16 + l16) * 128 + swz1;
    const char* rdB0 = (const char*)SM + 65536 + (wn * 16 + l16) * 128 + swz0;
    const char* rdB1 = (const char*)SM + 65536 + (wn * 16 + l16) * 128 + swz1;

    floatx4 acc[8][4];
    #pragma unroll
    for (int m = 0; m < 8; ++m)
        #pragma unroll
        for (int nt = 0; nt < 4; ++nt)
            acc[m][nt] = {0.f, 0.f, 0.f, 0.f};
    bf16x8 afr[4], bfr[4];

    // ---- prologue: K-tile 0 fully + {A-lo,B-lo}(1); vmcnt(4) leaves newest 2
    stA(0, 0, 0);      stB(0, 0, 0);
    stA(1, 0, 0);      stB(1, 0, 0);
    stA(0, 1, 32768);  stB(0, 1, 32768);
    VM4;
    BARR;

    // ---- main loop: 12 K-tiles, buffers alternate by parity
    #pragma unroll
    for (int ktp = 0; ktp < 6; ++ktp) {
        KTILE(0,     32768, ktp * 2);
        KTILE(32768, 0,     ktp * 2 + 1);
    }

    // ---- epilogue
    if constexpr (MODE == MODE_OUT) {
        #pragma unroll
        for (int nt = 0; nt < 4; ++nt) {
            const int n = n0 + nt * 64 + wn * 16 + l16;
            const float bv = bias[n];
            #pragma unroll
            for (int m = 0; m < 8; ++m)
                #pragma unroll
                for (int r = 0; r < 4; ++r) {
                    const int mm = m0 + m * 32 + wm * 16 + quad * 4 + r;
                    Op[(size_t)mm * kD + n] = acc[m][nt][r] + bv;
                }
        }
    } else {
        const int proj = n_tile / 3;   // 0=Q, 1=K, 2=V (block-uniform)
        if (proj < 2) {
            unsigned short* dst = proj ? Kp : Qp;
            // Q: fold softmax scale AND log2(e) so attention uses raw v_exp.
            const float scale = proj ? 1.0f : 0.125f * 1.44269504088896341f;
            #pragma unroll
            for (int nt = 0; nt < 4; ++nt) {
                const int n = n0 + nt * 64 + wn * 16 + l16;
                const float bv = bias[n];
                const int col = n - proj * kD;
                const int dh = col & 63;
                const int odd = l16 & 1;
                #pragma unroll
                for (int m = 0; m < 8; ++m)
                    #pragma unroll
                    for (int r = 0; r < 4; ++r) {
                        const int mm = m0 + m * 32 + wm * 16 + quad * 4 + r;
                        const float val = acc[m][nt][r] + bv;
                        const float px = __shfl_xor(val, 1);
                        const unsigned u = csT[(size_t)mm * 64 + dh];
                        const float c = bf2f((unsigned short)(u & 0xffffu));
                        const float s = bf2f((unsigned short)(u >> 16));
                        const float out = odd ? (val * c + px * s) : (val * c - px * s);
                        dst[(size_t)mm * kD + col] = f2bf(out * scale);
                    }
            }
        } else {
            #pragma unroll
            for (int nt = 0; nt < 4; ++nt) {
                const int n = n0 + nt * 64 + wn * 16 + l16;
                const float bv = bias[n];
                const int col = n - 2 * kD;
                const int h = col >> 6, dh = col & 63;
                #pragma unroll
                for (int m = 0; m < 8; ++m) {
                    const int m_r0 = m0 + m * 32 + wm * 16 + quad * 4;
                    const int b = m_r0 / kS;
                    const int s = m_r0 - b * kS;
                    ushort4 pk;
                    pk.x = f2bf(acc[m][nt][0] + bv);
                    pk.y = f2bf(acc[m][nt][1] + bv);
                    pk.z = f2bf(acc[m][nt][2] + bv);
                    pk.w = f2bf(acc[m][nt][3] + bv);
                    *(ushort4*)(Vtp + (size_t)((b * kH + h) * 64 + dh) * kSP + s) = pk;
                }
            }
        }
    }
}

// ---------------------------------------------------------------------------
// Flash attention, BR=256 (8 waves x 32 q-rows), BC=64. One latency-pass:
// 192 bh x 4 qt = 768 blocks == 256 CUs x 3 co-resident (LDS 48KB) -> the
// former 2-pass quantization (1344 blocks) collapses to 1 pass.
// Per-wave math identical to round 5: swapped QK^T (T12), in-register P via
// cvt_pk + permlane32/16, row-sum on the matrix pipe, raw v_exp (2^x),
// K/V triple-buffered depth-2 counted vmcnt (4 -> 2 -> 0; 2-gll batches).
// Q (256x64 = 32KB) staged through the 48KB KV arena, dead before K/V
// prologue reuses it. qt=3 tail: rows clamped to 783 on load, stores guarded.
// ---------------------------------------------------------------------------
__global__ __launch_bounds__(512)
void flash_attn(const unsigned short* __restrict__ Qg,
                const unsigned short* __restrict__ Kg,
                const unsigned short* __restrict__ Vtg,
                unsigned short* __restrict__ Og)
{
    __shared__ unsigned short KV[3][8192];   // 48KB; [buf]: K @ [0], V @ [4096]

    const int lin   = blockIdx.x;            // 0..767 (192 bh x 4 qt)
    const int group = lin / 32;              // 24 groups of 8 bh x 4 qt
    const int rem   = lin - group * 32;
    const int bh = group * 8 + (rem & 7);
    const int qt = rem >> 3;                 // 0..3
    const int b = bh / kH, h = bh - b * kH;
    const int tid = threadIdx.x, wave = tid >> 6, lane = tid & 63;
    const int quad = lane >> 4, l16 = lane & 15;
    const int q0 = qt * 256;
    const size_t rowBase = (size_t)(b * kS) * kD + h * 64;
    unsigned short* KVf = &KV[0][0];         // flat 48KB arena

    // ---- stage Q (256x64, 32KB) into arena, swizzled, via gll (4/thread)
    #pragma unroll
    for (int j = 0; j < 4; ++j) {
        const int idx = (wave * 4 + j) * 64 + lane;     // 0..2047
        const int row = idx >> 3, slot = idx & 7, seg = slot ^ (row & 7);
        int qr = q0 + row;                               // clamp tail reads
        if (qr >= kS) qr = kS - 1;
        gload_lds16(Qg + rowBase + (size_t)qr * kD + seg * 8,
                    (char*)KVf + (wave * 4 + j) * 1024);
    }
    __syncthreads();
    bf16x8 aq[2][2];
    #pragma unroll
    for (int mt = 0; mt < 2; ++mt)
        #pragma unroll
        for (int ch = 0; ch < 2; ++ch) {
            const int row = wave * 32 + mt * 16 + l16;   // 0..255
            const int slot = (ch * 4 + quad) ^ (row & 7);
            aq[mt][ch] = *(const bf16x8*)&KVf[row * 64 + slot * 8];
        }
    __syncthreads();   // aq reads drained before prologue overwrites arena

    // staging chunk geometry: K tile 512 chunks + V tile 512; 2 gll/thread
    const int crow = tid >> 3;                       // 0..63
    const int cseg = (lane & 7) ^ (crow & 7);

    // stage one K/V tile into buffer `buf`
    auto stage = [&](int kt, int buf) {
        const int kr = kt * 64;
        gload_lds16(Kg + rowBase + (size_t)(kr + crow) * kD + cseg * 8,
                    &KV[buf][wave * 512]);
        gload_lds16(Vtg + (size_t)(bh * 64 + crow) * kSP + kr + cseg * 8,
                    &KV[buf][4096 + wave * 512]);
    };

    // prologue: batches 0,1 into buf0,buf1 (prefetch depth 2)
    stage(0, 0);
    stage(1, 1);

    floatx4 oacc[2][4];
    #pragma unroll
    for (int mt = 0; mt < 2; ++mt)
        #pragma unroll
        for (int nt = 0; nt < 4; ++nt)
            oacc[mt][nt] = {0.f, 0.f, 0.f, 0.f};
    floatx4 lsum[2];
    lsum[0] = {0.f, 0.f, 0.f, 0.f};
    lsum[1] = {0.f, 0.f, 0.f, 0.f};
    const bf16x8 onesb = { 16256, 16256, 16256, 16256,
                           16256, 16256, 16256, 16256 };   // bf16 1.0 x8

    int cur = 0;   // kt % 3
    int pre = 2;   // (kt+2) % 3
    for (int kt = 0; kt < 13; ++kt) {
        asm volatile("s_barrier" ::: "memory");   // WAR: readers of buf[pre] done
        if (kt < 11) stage(kt + 2, pre);
        if (kt < 11)       asm volatile("s_waitcnt vmcnt(4)" ::: "memory");
        else if (kt == 11) asm volatile("s_waitcnt vmcnt(2)" ::: "memory");
        else               asm volatile("s_waitcnt vmcnt(0)" ::: "memory");
        asm volatile("s_barrier" ::: "memory");   // RAW: batch kt visible to all

        const unsigned short* Ks = &KV[cur][0];
        const unsigned short* Vs = &KV[cur][4096];

        // S^T = K Q^T  (swapped): lane(quad,l16) reg r of sc[nt][mt] =
        //   S[k = nt*16+quad*4+r][q = wave*32 + mt*16+l16]
        bf16x8 bk[4][2];
        #pragma unroll
        for (int nt = 0; nt < 4; ++nt)
            #pragma unroll
            for (int ch = 0; ch < 2; ++ch) {
                const int row = nt * 16 + l16;
                const int slot = (ch * 4 + quad) ^ (row & 7);
                bk[nt][ch] = *(const bf16x8*)&Ks[row * 64 + slot * 8];
            }

        floatx4 sc[4][2];
        __builtin_amdgcn_s_setprio(1);
        #pragma unroll
        for (int nt = 0; nt < 4; ++nt)
            #pragma unroll
            for (int mt = 0; mt < 2; ++mt) {
                sc[nt][mt] = {0.f, 0.f, 0.f, 0.f};
                sc[nt][mt] = __builtin_amdgcn_mfma_f32_16x16x32_bf16(
                    bk[nt][0], aq[mt][0], sc[nt][mt], 0, 0, 0);
                sc[nt][mt] = __builtin_amdgcn_mfma_f32_16x16x32_bf16(
                    bk[nt][1], aq[mt][1], sc[nt][mt], 0, 0, 0);
            }
        __builtin_amdgcn_s_setprio(0);

        if (kt == 12) {   // valid keys 768..783 = local k 0..15 (nt==0 only)
            #pragma unroll
            for (int nt = 1; nt < 4; ++nt)
                #pragma unroll
                for (int mt = 0; mt < 2; ++mt)
                    #pragma unroll
                    for (int r = 0; r < 4; ++r) sc[nt][mt][r] = -1e30f;
        }

        // P = 2^S' (raw v_exp), in place
        #pragma unroll
        for (int nt = 0; nt < 4; ++nt)
            #pragma unroll
            for (int mt = 0; mt < 2; ++mt)
                #pragma unroll
                for (int r = 0; r < 4; ++r)
                    sc[nt][mt][r] = fast_exp2(sc[nt][mt][r]);

        // In-register P -> PV A-fragments via cvt_pk + permlane swaps.
        bf16x8 ap[2][2];
        #pragma unroll
        for (int mt = 0; mt < 2; ++mt) {
            unsigned L0 = cvtpk(sc[0][mt][0], sc[0][mt][1]);
            unsigned H0 = cvtpk(sc[0][mt][2], sc[0][mt][3]);
            unsigned L1 = cvtpk(sc[1][mt][0], sc[1][mt][1]);
            unsigned H1 = cvtpk(sc[1][mt][2], sc[1][mt][3]);
            unsigned L2 = cvtpk(sc[2][mt][0], sc[2][mt][1]);
            unsigned H2 = cvtpk(sc[2][mt][2], sc[2][mt][3]);
            unsigned L3 = cvtpk(sc[3][mt][0], sc[3][mt][1]);
            unsigned H3 = cvtpk(sc[3][mt][2], sc[3][mt][3]);
            pl32(L0, L1); pl16(L0, L1);   // ks=0
            pl32(H0, H1); pl16(H0, H1);
            ap[mt][0] = mk8(L0, H0, L1, H1);
            pl32(L2, L3); pl16(L2, L3);   // ks=1
            pl32(H2, H3); pl16(H2, H3);
            ap[mt][1] = mk8(L2, H2, L3, H3);
        }

        // O += P V ; lsum += P * 1
        __builtin_amdgcn_s_setprio(1);
        #pragma unroll
        for (int ks = 0; ks < 2; ++ks) {
            #pragma unroll
            for (int nt = 0; nt < 4; ++nt) {
                const int row = nt * 16 + l16;
                const int slot = (ks * 4 + quad) ^ (row & 7);
                const bf16x8 bv = *(const bf16x8*)&Vs[row * 64 + slot * 8];
                #pragma unroll
                for (int mt = 0; mt < 2; ++mt)
                    oacc[mt][nt] = __builtin_amdgcn_mfma_f32_16x16x32_bf16(
                        ap[mt][ks], bv, oacc[mt][nt], 0, 0, 0);
            }
            #pragma unroll
            for (int mt = 0; mt < 2; ++mt)
                lsum[mt] = __builtin_amdgcn_mfma_f32_16x16x32_bf16(
                    ap[mt][ks], onesb, lsum[mt], 0, 0, 0);
        }
        __builtin_amdgcn_s_setprio(0);

        cur = (cur == 2) ? 0 : cur + 1;
        pre = (pre == 2) ? 0 : pre + 1;
    }

    // lsum lane layout == oacc lane layout: reg r <-> q-row quad*4+r.
    #pragma unroll
    for (int mt = 0; mt < 2; ++mt)
        #pragma unroll
        for (int r = 0; r < 4; ++r) {
            const int srow = q0 + wave * 32 + mt * 16 + quad * 4 + r;
            if (srow < kS) {
                const float inv = 1.0f / lsum[mt][r];
                #pragma unroll
                for (int nt = 0; nt < 4; ++nt)
                    Og[rowBase + (size_t)srow * kD + nt * 16 + l16] =
                        f2bf(oacc[mt][nt][r] * inv);
            }
        }
}

// ---------------------------------------------------------------------------
extern "C" void kernel_launch(void* const* d_in, const int* in_sizes, int n_in,
                              void* d_out, int out_size, void* d_ws, size_t ws_size,
                              hipStream_t stream)
{
    (void)in_sizes; (void)n_in; (void)out_size; (void)ws_size;
    const float* hs  = (const float*)d_in[0];
    const float* rot = (const float*)d_in[1];
    const float* wq  = (const float*)d_in[2];
    const float* bq  = (const float*)d_in[3];
    const float* wk  = (const float*)d_in[4];
    const float* bk  = (const float*)d_in[5];
    const float* wv  = (const float*)d_in[6];
    const float* bv  = (const float*)d_in[7];
    const float* wo  = (const float*)d_in[8];
    const float* bo  = (const float*)d_in[9];

    char* ws = (char*)d_ws;
    // Layout (bytes):
    //   hsB/O : 0          .. 19,267,584   (bf16 [12544,768]; O aliases after QKV)
    //   wB    : 19,267,584 .. 23,986,176   (wq|wk|wv|wo bf16 = [2304+768, 768])
    //   csT   : 23,986,176 .. 27,197,440   (uint cos|sin bf16 [12544,64])
    //   biasC : 27,197,440 .. 27,206,656   (bq|bk|bv fp32)
    //   Q     : 27,206,656 .. 46,474,240
    //   K     : 46,474,240 .. 65,741,824
    //   Vt    : 65,741,824 .. 86,189,056   (bf16 [192*64, 832])
    unsigned short* hsB  = (unsigned short*)ws;
    unsigned short* wB   = (unsigned short*)(ws + 19267584);
    unsigned int*   csT  = (unsigned int*)(ws + 23986176);
    float*          biasC= (float*)(ws + 27197440);
    unsigned short* Q    = (unsigned short*)(ws + 27206656);
    unsigned short* K    = (unsigned short*)(ws + 46474240);
    unsigned short* Vt   = (unsigned short*)(ws + 65741824);
    unsigned short* O    = hsB;  // hsB dead after QKV GEMM

    convert_pre<<<dim3(12505), dim3(256), 0, stream>>>(hs, rot, wq, wk, wv, wo, bq, bk, bv,
                                                       hsB, wB, csT, biasC);
    // QKV: 49 m-tiles x 9 n-tiles = 441 blocks (6 groups of 72 + tail 9)
    gemm8<MODE_QKV><<<dim3(441), dim3(512), 0, stream>>>(
        hsB, wB, biasC, csT, Q, K, Vt, nullptr);
    // attention: 192 bh x 4 q-tiles of 256 rows = 768 blocks (one pass)
    flash_attn<<<dim3(768), dim3(512), 0, stream>>>(Q, K, Vt, O);
    // OUT: 49 x 3 = 147 blocks
    gemm8<MODE_OUT><<<dim3(147), dim3(512), 0, stream>>>(
        O, wB + 3 * kD * kD, bo, nullptr, nullptr, nullptr, nullptr, (float*)d_out);
}